// Round 1
// baseline (474.596 us; speedup 1.0000x reference)
//
#include <hip/hip_runtime.h>

// VectorAttention: B=4, C=32, H=256, W=256, HID=64
// d_in order: x, Wqkv, W1, b1, ln_w, ln_b, W2, b2, Wg, bg (all float32)
// out: (B, C, H, W) float32
//
// ws layout: [0, 25165824) floats : qkv (B, 96, H, W)
//            [25165824, 25167872) : W2T (64 x 32), W2T[d*32+c] = W2[c*64+d]

#define HWm 65536   // H*W
#define NPIX 262144 // B*H*W

// Kernel 1: qkv = Wqkv @ x  (into ws), out = Wg @ x + bg + x, plus W2 transpose.
__global__ __launch_bounds__(256) void qkv_base_kernel(
    const float* __restrict__ x, const float* __restrict__ Wqkv,
    const float* __restrict__ Wg, const float* __restrict__ bg,
    const float* __restrict__ W2, float* __restrict__ qkv,
    float* __restrict__ W2T, float* __restrict__ out)
{
    const int tid = threadIdx.x;
    if (blockIdx.x == 0) {
        for (int i = tid; i < 2048; i += 256) {
            int d = i >> 5, c = i & 31;
            W2T[i] = W2[c * 64 + d];
        }
    }
    const int pix = blockIdx.x * 256 + tid;
    const int b = pix >> 16;
    const int rem = pix & 65535;

    const float* xp = x + b * (32 * HWm) + rem;
    float xv[32];
#pragma unroll
    for (int c = 0; c < 32; ++c) xv[c] = xp[c * HWm];

    float* qkvp = qkv + b * (96 * HWm) + rem;
    for (int o = 0; o < 96; ++o) {
        float acc = 0.f;
        const float* wr = Wqkv + o * 32;
#pragma unroll
        for (int c = 0; c < 32; ++c) acc = fmaf(wr[c], xv[c], acc);
        qkvp[o * HWm] = acc;
    }

    float* outp = out + b * (32 * HWm) + rem;
    for (int o = 0; o < 32; ++o) {
        float acc = bg[o];
        const float* wr = Wg + o * 32;
#pragma unroll
        for (int c = 0; c < 32; ++c) acc = fmaf(wr[c], xv[c], acc);
        outp[o * HWm] = acc + xp[o * HWm];  // + x residual
    }
}

// Kernel 2: per-pixel neighborhood attention. One thread = one pixel.
// Block = 256 threads = one image row (b, h). LDS holds per-thread hid[64].
__global__ __launch_bounds__(256, 2) void attn_kernel(
    const float* __restrict__ qkv, const float* __restrict__ W1,
    const float* __restrict__ b1, const float* __restrict__ lnw,
    const float* __restrict__ lnb, const float* __restrict__ W2T,
    const float* __restrict__ b2, float* __restrict__ out)
{
    __shared__ float hidL[64 * 256];  // [d][tid], conflict-free (stride-1 across lanes)
    const int tid = threadIdx.x;
    const int pix = blockIdx.x * 256 + tid;
    const int b = pix >> 16;
    const int rem = pix & 65535;
    const int h = rem >> 8;
    const int w = rem & 255;

    const float* qp    = qkv + b * (96 * HWm) + rem;
    const float* kbase = qkv + b * (96 * HWm) + 32 * HWm;
    const float* vbase = qkv + b * (96 * HWm) + 64 * HWm;

    float q[32];
#pragma unroll
    for (int c = 0; c < 32; ++c) q[c] = qp[c * HWm];

    float ssum[32], wv[32];
#pragma unroll
    for (int c = 0; c < 32; ++c) { ssum[c] = 0.f; wv[c] = 0.f; }

    for (int n = 0; n < 9; ++n) {
        const int dy = n / 3 - 1, dx = n % 3 - 1;
        const int hh = h + dy, ww = w + dx;
        const bool valid = ((unsigned)hh < 256u) && ((unsigned)ww < 256u);
        const int noff = valid ? (hh * 256 + ww) : 0;  // clamped in-bounds addr

        // dq = q - k_neighbor (zero-padded)
        float dq[32];
#pragma unroll
        for (int c = 0; c < 32; ++c) {
            float kv = kbase[c * HWm + noff];
            dq[c] = q[c] - (valid ? kv : 0.f);
        }

        // hid[d] = W1[d,:] . dq + b1[d]  -> LDS (weights via uniform s_load)
        for (int d = 0; d < 64; ++d) {
            float acc = b1[d];
            const float* w1r = W1 + d * 32;
#pragma unroll
            for (int c = 0; c < 32; ++c) acc = fmaf(w1r[c], dq[c], acc);
            hidL[d * 256 + tid] = acc;
        }

        // LayerNorm stats (biased var; denominator is std + eps per reference)
        float sum = 0.f, sumsq = 0.f;
        for (int d = 0; d < 64; ++d) {
            float hv = hidL[d * 256 + tid];
            sum += hv;
            sumsq = fmaf(hv, hv, sumsq);
        }
        const float mean = sum * (1.f / 64.f);
        float var = sumsq * (1.f / 64.f) - mean * mean;
        var = fmaxf(var, 0.f);
        const float inv = 1.f / (sqrtf(var) + 1e-5f);

        // scores[c] = W2[c,:] . relu(LN(hid)) + b2[c]
        float sc[32];
#pragma unroll
        for (int c = 0; c < 32; ++c) sc[c] = b2[c];
        for (int d = 0; d < 64; ++d) {
            float hv = hidL[d * 256 + tid];
            float hn = (hv - mean) * inv;
            hn = fmaf(hn, lnw[d], lnb[d]);
            hn = fmaxf(hn, 0.f);
            const float* w2r = W2T + d * 32;
#pragma unroll
            for (int c = 0; c < 32; ++c) sc[c] = fmaf(w2r[c], hn, sc[c]);
        }

        // online softmax accumulation (scores bounded ~|4| by LN -> no max needed)
#pragma unroll
        for (int c = 0; c < 32; ++c) {
            float e = __expf(sc[c]);
            float vv = vbase[c * HWm + noff];
            vv = valid ? vv : 0.f;
            ssum[c] += e;
            wv[c] = fmaf(e, vv, wv[c]);
        }
    }

    float* outp = out + b * (32 * HWm) + rem;
#pragma unroll
    for (int c = 0; c < 32; ++c) {
        outp[c * HWm] += wv[c] / ssum[c];
    }
}

extern "C" void kernel_launch(void* const* d_in, const int* in_sizes, int n_in,
                              void* d_out, int out_size, void* d_ws, size_t ws_size,
                              hipStream_t stream) {
    const float* x    = (const float*)d_in[0];
    const float* Wqkv = (const float*)d_in[1];
    const float* W1   = (const float*)d_in[2];
    const float* b1   = (const float*)d_in[3];
    const float* lnw  = (const float*)d_in[4];
    const float* lnb  = (const float*)d_in[5];
    const float* W2   = (const float*)d_in[6];
    const float* b2   = (const float*)d_in[7];
    const float* Wg   = (const float*)d_in[8];
    const float* bg   = (const float*)d_in[9];
    float* out = (float*)d_out;

    float* qkv = (float*)d_ws;                 // 25,165,824 floats
    float* W2T = qkv + 25165824;               // 2,048 floats

    const int nblocks = NPIX / 256;            // 1024
    qkv_base_kernel<<<nblocks, 256, 0, stream>>>(x, Wqkv, Wg, bg, W2, qkv, W2T, out);
    attn_kernel<<<nblocks, 256, 0, stream>>>(qkv, W1, b1, lnw, lnb, W2T, b2, out);
}